// Round 11
// baseline (200.381 us; speedup 1.0000x reference)
//
#include <hip/hip_runtime.h>
#include <hip/hip_bf16.h>

#define B_   64
#define L_   512
#define H2_  1024
#define M_   (B_ * L_)     // 32768
#define KSPLIT 16
#define KCH  (H2_ / KSPLIT)   // 64

typedef short bf16x8 __attribute__((ext_vector_type(8)));
typedef float f32x4  __attribute__((ext_vector_type(4)));
typedef ushort ushort8_t __attribute__((ext_vector_type(8)));

__device__ __forceinline__ ushort f2bf(float f) {
    uint x = __float_as_uint(f);
    uint r = (x + 0x7FFFu + ((x >> 16) & 1u)) >> 16;
    return (ushort)r;
}

__device__ __forceinline__ float fast_tanh(float x) {
    float ax = fabsf(x);
    float e  = __expf(-2.0f * ax);
    float t  = 1.0f - 2.0f * e / (1.0f + e);
    return copysignf(t, x);
}

__device__ __forceinline__ void gload_lds16(const ushort* g, ushort* l) {
    __builtin_amdgcn_global_load_lds(
        (const __attribute__((address_space(1))) void*)g,
        (__attribute__((address_space(3))) void*)l, 16, 0, 0);
}

// -------------------------------------------------------------------------
// convertA: pai_q fp32 -> bf16 row-major.
// -------------------------------------------------------------------------
__global__ __launch_bounds__(256) void convertA_kernel(
    const float* __restrict__ in, ushort* __restrict__ out)
{
    size_t i = ((size_t)blockIdx.x * 256 + threadIdx.x) * 8;
    float4 a = *(const float4*)&in[i];
    float4 b = *(const float4*)&in[i + 4];
    ushort8_t h;
    h[0] = f2bf(a.x); h[1] = f2bf(a.y); h[2] = f2bf(a.z); h[3] = f2bf(a.w);
    h[4] = f2bf(b.x); h[5] = f2bf(b.y); h[6] = f2bf(b.z); h[7] = f2bf(b.w);
    *(ushort8_t*)&out[i] = h;
}

// -------------------------------------------------------------------------
// convertB: W_q [k][n] fp32 -> Bbf [n][k] bf16 (transpose via LDS 32x33).
// -------------------------------------------------------------------------
__global__ __launch_bounds__(256) void convertB_kernel(
    const float* __restrict__ W, ushort* __restrict__ out)
{
    __shared__ float t[32][33];
    int tx = threadIdx.x & 31, ty = threadIdx.x >> 5;
    int k0 = blockIdx.x * 32, n0 = blockIdx.y * 32;
    #pragma unroll
    for (int r = 0; r < 4; ++r)
        t[ty + r * 8][tx] = W[(size_t)(k0 + ty + r * 8) * H2_ + n0 + tx];
    __syncthreads();
    #pragma unroll
    for (int r = 0; r < 4; ++r)
        out[(size_t)(n0 + ty + r * 8) * H2_ + k0 + tx] = f2bf(t[tx][ty + r * 8]);
}

// -------------------------------------------------------------------------
// dec split-K
// -------------------------------------------------------------------------
__global__ __launch_bounds__(256) void dec_split_kernel(
    const float* __restrict__ s_t_hat, const float* __restrict__ Wqs,
    float* __restrict__ dec_part)
{
    const int t  = threadIdx.x;
    const int n  = blockIdx.x * 64 + (t & 63);
    const int k0 = blockIdx.y * KCH;
    const int bg = t >> 6;

    float acc[16];
    #pragma unroll
    for (int i = 0; i < 16; ++i) acc[i] = 0.f;

    for (int k8 = 0; k8 < KCH; k8 += 8) {
        float w[8];
        #pragma unroll
        for (int kk = 0; kk < 8; ++kk)
            w[kk] = Wqs[(size_t)(k0 + k8 + kk) * H2_ + n];
        #pragma unroll
        for (int i = 0; i < 16; ++i) {
            const float* srow = &s_t_hat[(bg * 16 + i) * H2_ + k0 + k8];
            #pragma unroll
            for (int kk = 0; kk < 8; ++kk)
                acc[i] += srow[kk] * w[kk];
        }
    }
    #pragma unroll
    for (int i = 0; i < 16; ++i)
        dec_part[(size_t)blockIdx.y * (B_ * H2_) + (bg * 16 + i) * H2_ + n] = acc[i];
}

__global__ __launch_bounds__(256) void dec_reduce_kernel(
    const float* __restrict__ dec_part, const float* __restrict__ bqs,
    float* __restrict__ dec)
{
    int i = blockIdx.x * 256 + threadIdx.x;
    float s = bqs[i & (H2_ - 1)];
    #pragma unroll
    for (int p = 0; p < KSPLIT; ++p) s += dec_part[(size_t)p * (B_ * H2_) + i];
    dec[i] = s;
}

// -------------------------------------------------------------------------
// Fallback dec (monolithic) — only if ws too small.
// -------------------------------------------------------------------------
__global__ __launch_bounds__(256) void dec_kernel(
    const float* __restrict__ s_t_hat, const float* __restrict__ Wqs,
    const float* __restrict__ bqs, float* __restrict__ dec)
{
    int n  = blockIdx.x * 256 + threadIdx.x;
    int b0 = blockIdx.y * 4;
    float a0 = 0.f, a1 = 0.f, a2 = 0.f, a3 = 0.f;
    for (int h = 0; h < H2_; ++h) {
        float w = Wqs[h * H2_ + n];
        a0 += s_t_hat[(b0 + 0) * H2_ + h] * w;
        a1 += s_t_hat[(b0 + 1) * H2_ + h] * w;
        a2 += s_t_hat[(b0 + 2) * H2_ + h] * w;
        a3 += s_t_hat[(b0 + 3) * H2_ + h] * w;
    }
    float bias = bqs[n];
    dec[(b0 + 0) * H2_ + n] = a0 + bias;
    dec[(b0 + 1) * H2_ + n] = a1 + bias;
    dec[(b0 + 2) * H2_ + n] = a2 + bias;
    dec[(b0 + 3) * H2_ + n] = a3 + bias;
}

// -------------------------------------------------------------------------
// score v5: 256x256 tile, BK=32, 8 waves (2m x 4n), 4 phases/K-tile,
// double-buffered LDS (64 KB static), counted vmcnt(2) once per K-tile,
// setprio around MFMA clusters, XOR-swizzled LDS (key (row>>1)&3, 2-way max),
// XCD-chunked n-fastest grid swizzle.
//
// Ledger (per-wave gloads, 2 per stage-call):
//   prologue: B(0) A(0) B(1)            -> vmcnt(2): B(0),A(0) landed
//   tile u: P1 stages A(u+1) [u<31]; P2 stages B(u+2) [u<30]
//   u.P4-close: vmcnt(2) leaves only B(u+2) pair in flight; barrier makes
//   tile u+1 (A @u.P1, B @(u-1).P2 — both older) visible to all waves.
//   Overwrite safety: B slots read only in P1 (regs hold B all tile);
//   A(u+1) overwrites tile u-1's A, dead since (u-1).P4-close.
// -------------------------------------------------------------------------
#define BM5 256
#define BN5 256
#define BK5 32

__global__ __launch_bounds__(512, 2) void score_kernel5(
    const ushort* __restrict__ Abf,  // (M, 1024) bf16
    const ushort* __restrict__ Bbf,  // (1024 n, 1024 k) bf16
    const float* __restrict__ dec,
    const float* __restrict__ cov,
    const float* __restrict__ Wc,
    const float* __restrict__ vq,
    float* __restrict__ scores_part) // (16, M)
{
    __shared__ ushort As[2][BM5 * BK5];   // 2 x 16 KB
    __shared__ ushort Bs[2][BN5 * BK5];   // 2 x 16 KB

    const int tid  = threadIdx.x;
    const int lane = tid & 63;
    const int wave = tid >> 6;          // 0..7
    const int wm   = wave >> 2;         // 0..1
    const int wn   = wave & 3;          // 0..3

    // XCD-chunked, n-fastest swizzle over 512 blocks (bijective)
    const int bid  = blockIdx.x;
    const int xcd  = bid & 7;
    const int slot = bid >> 3;          // 0..63
    const int mb   = xcd * 16 + (slot >> 2);   // 0..127
    const int nb   = slot & 3;                  // 0..3
    const int m0   = mb * BM5;
    const int n0   = nb * BN5;

    f32x4 acc[8][4] = {};

    // staging: one matrix-half (128 rows x 64B) = 512 thr x 16B = 1 gload
    const int s_row = tid >> 2;                                // 0..127
    const int s_col = ((tid & 3) ^ ((s_row >> 1) & 3)) * 8;    // swizzled src col

    // read mapping
    const int fr = lane & 15;
    const int fg = lane >> 4;            // 0..3 = k-chunk
    const int cA = ((fg ^ ((fr >> 1) & 3)) * 8);   // swizzled chunk offset

    #define STAGE_A(tile_) do {                                            \
        ushort* lds_ = &As[(tile_) & 1][0];                                \
        const ushort* gp_ = Abf + (size_t)(m0 + s_row) * H2_ + (tile_) * BK5 + s_col; \
        gload_lds16(gp_,                     lds_ + wave * 512);           \
        gload_lds16(gp_ + (size_t)128 * H2_, lds_ + 4096 + wave * 512);    \
    } while (0)
    #define STAGE_B(tile_) do {                                            \
        ushort* lds_ = &Bs[(tile_) & 1][0];                                \
        const ushort* gp_ = Bbf + (size_t)(n0 + s_row) * H2_ + (tile_) * BK5 + s_col; \
        gload_lds16(gp_,                     lds_ + wave * 512);           \
        gload_lds16(gp_ + (size_t)128 * H2_, lds_ + 4096 + wave * 512);    \
    } while (0)

    // prologue: B(0), A(0), B(1) staged; wait for first 4 (B0, A0)
    STAGE_B(0);
    STAGE_A(0);
    STAGE_B(1);
    asm volatile("s_waitcnt vmcnt(2)" ::: "memory");
    __builtin_amdgcn_s_barrier();

    for (int u = 0; u < 32; ++u) {
        const int cur = u & 1;
        const ushort* Ab = &As[cur][0];
        const ushort* Bb = &Bs[cur][0];
        bf16x8 bfr[4];

        #pragma unroll
        for (int p = 0; p < 4; ++p) {
            bf16x8 af0, af1;
            // ---- opening region: ds_reads + stage issues ----
            if (p == 0) {
                #pragma unroll
                for (int j = 0; j < 4; ++j)
                    bfr[j] = *(const bf16x8*)&Bb[(wn * 64 + j * 16 + fr) * BK5 + cA];
                af0 = *(const bf16x8*)&Ab[(wm * 128 + 0 * 16 + fr) * BK5 + cA];
                af1 = *(const bf16x8*)&Ab[(wm * 128 + 1 * 16 + fr) * BK5 + cA];
                if (u < 31) STAGE_A(u + 1);
            } else {
                af0 = *(const bf16x8*)&Ab[(wm * 128 + (2 * p) * 16 + fr) * BK5 + cA];
                af1 = *(const bf16x8*)&Ab[(wm * 128 + (2 * p + 1) * 16 + fr) * BK5 + cA];
                if (p == 1 && u < 30) STAGE_B(u + 2);
            }
            __builtin_amdgcn_s_barrier();                 // barrier1
            __builtin_amdgcn_sched_barrier(0);
            __builtin_amdgcn_s_setprio(1);
            #pragma unroll
            for (int j = 0; j < 4; ++j) {
                acc[2 * p][j]     = __builtin_amdgcn_mfma_f32_16x16x32_bf16(af0, bfr[j], acc[2 * p][j], 0, 0, 0);
                acc[2 * p + 1][j] = __builtin_amdgcn_mfma_f32_16x16x32_bf16(af1, bfr[j], acc[2 * p + 1][j], 0, 0, 0);
            }
            __builtin_amdgcn_s_setprio(0);
            if (p < 3) {
                __builtin_amdgcn_s_barrier();             // barrier2
                __builtin_amdgcn_sched_barrier(0);
            }
        }
        // P4 closing: counted vmcnt, then barrier (skip on last tile)
        if (u < 31) {
            if (u < 30) { asm volatile("s_waitcnt vmcnt(2)" ::: "memory"); }
            else        { asm volatile("s_waitcnt vmcnt(0)" ::: "memory"); }
            __builtin_amdgcn_s_barrier();
            __builtin_amdgcn_sched_barrier(0);
        }
    }

    // ---- epilogue: + dec + cov*Wc -> tanh -> * vq -> row-sum -> partial ----
    const int b = mb >> 1;               // 256-row block within one batch
    float dec4[4], wc4[4], vq4[4];
    #pragma unroll
    for (int j = 0; j < 4; ++j) {
        int n = n0 + wn * 64 + j * 16 + fr;
        dec4[j] = dec[b * H2_ + n];
        wc4[j]  = Wc[n];
        vq4[j]  = vq[n];
    }
    #pragma unroll
    for (int i = 0; i < 8; ++i) {
        #pragma unroll
        for (int r = 0; r < 4; ++r) {
            int m = m0 + wm * 128 + i * 16 + fg * 4 + r;
            float cv = cov[b * L_ + (m & (L_ - 1))];
            float s = 0.f;
            #pragma unroll
            for (int j = 0; j < 4; ++j) {
                float att = acc[i][j][r] + dec4[j] + cv * wc4[j];
                s += fast_tanh(att) * vq4[j];
            }
            s += __shfl_xor(s, 1);
            s += __shfl_xor(s, 2);
            s += __shfl_xor(s, 4);
            s += __shfl_xor(s, 8);
            if (fr == 0)
                scores_part[(size_t)(nb * 4 + wn) * M_ + m] = s;
        }
    }
    #undef STAGE_A
    #undef STAGE_B
}

// -------------------------------------------------------------------------
// Fallback score (fp32 inputs, reg-staged) — only if ws too small.
// -------------------------------------------------------------------------
#define BM 128
#define BN 128
#define LDK 40
__global__ __launch_bounds__(256) void score_kernel_fb(
    const float* __restrict__ A, const float* __restrict__ Bmat,
    const float* __restrict__ dec, const float* __restrict__ cov,
    const float* __restrict__ Wc, const float* __restrict__ vq,
    float* __restrict__ scores_part)
{
    __shared__ ushort As[BM * LDK];
    __shared__ ushort Bs[BN * LDK];
    const int tid  = threadIdx.x;
    const int lane = tid & 63;
    const int wave = tid >> 6;
    const int wm = wave >> 1, wn = wave & 1;
    const int m0 = blockIdx.x * BM;
    const int n0 = blockIdx.y * BN;
    f32x4 acc[4][4] = {};
    const int a_row = tid >> 3;
    const int a_kc  = (tid & 7) * 4;
    const int b_k  = tid >> 5;
    const int b_nc = (tid & 31) * 4;
    const int fr = lane & 15;
    const int fg = lane >> 4;
    for (int kt = 0; kt < H2_; kt += 32) {
        #pragma unroll
        for (int p = 0; p < 4; ++p) {
            int row = a_row + p * 32;
            float4 v = *(const float4*)&A[(size_t)(m0 + row) * H2_ + kt + a_kc];
            ushort4 h;
            h.x = f2bf(v.x); h.y = f2bf(v.y); h.z = f2bf(v.z); h.w = f2bf(v.w);
            *(ushort4*)&As[row * LDK + a_kc] = h;
        }
        #pragma unroll
        for (int p = 0; p < 4; ++p) {
            int k = b_k + p * 8;
            float4 v = *(const float4*)&Bmat[(size_t)(kt + k) * H2_ + n0 + b_nc];
            Bs[(b_nc + 0) * LDK + k] = f2bf(v.x);
            Bs[(b_nc + 1) * LDK + k] = f2bf(v.y);
            Bs[(b_nc + 2) * LDK + k] = f2bf(v.z);
            Bs[(b_nc + 3) * LDK + k] = f2bf(v.w);
        }
        __syncthreads();
        bf16x8 af[4], bfr[4];
        #pragma unroll
        for (int i = 0; i < 4; ++i)
            af[i] = *(const bf16x8*)&As[(wm * 64 + i * 16 + fr) * LDK + fg * 8];
        #pragma unroll
        for (int j = 0; j < 4; ++j)
            bfr[j] = *(const bf16x8*)&Bs[(wn * 64 + j * 16 + fr) * LDK + fg * 8];
        #pragma unroll
        for (int i = 0; i < 4; ++i)
            #pragma unroll
            for (int j = 0; j < 4; ++j)
                acc[i][j] = __builtin_amdgcn_mfma_f32_16x16x32_bf16(af[i], bfr[j], acc[i][j], 0, 0, 0);
        __syncthreads();
    }
    const int b = m0 >> 9;
    float dec4[4], wc4[4], vq4[4];
    #pragma unroll
    for (int j = 0; j < 4; ++j) {
        int n = n0 + wn * 64 + j * 16 + fr;
        dec4[j] = dec[b * H2_ + n];
        wc4[j]  = Wc[n];
        vq4[j]  = vq[n];
    }
    #pragma unroll
    for (int i = 0; i < 4; ++i) {
        #pragma unroll
        for (int r = 0; r < 4; ++r) {
            int ml = wm * 64 + i * 16 + fg * 4 + r;
            int m  = m0 + ml;
            float cv = cov[b * L_ + (m & (L_ - 1))];
            float s = 0.f;
            #pragma unroll
            for (int j = 0; j < 4; ++j) {
                float att = acc[i][j][r] + dec4[j] + cv * wc4[j];
                s += fast_tanh(att) * vq4[j];
            }
            s += __shfl_xor(s, 1);
            s += __shfl_xor(s, 2);
            s += __shfl_xor(s, 4);
            s += __shfl_xor(s, 8);
            if (fr == 0)
                scores_part[(size_t)(blockIdx.y * 2 + wn) * M_ + m] = s;
        }
    }
}

// -------------------------------------------------------------------------
__global__ __launch_bounds__(512) void softmax_kernel(
    const float* __restrict__ scores_part,
    const float* __restrict__ mask,
    const float* __restrict__ cov,
    float* __restrict__ out_alpha,
    float* __restrict__ out_newcov)
{
    int b = blockIdx.x;
    int l = threadIdx.x;
    int m = b * L_ + l;
    float s = 0.f;
    #pragma unroll
    for (int p = 0; p < 16; ++p) s += scores_part[(size_t)p * M_ + m];
    __shared__ float red[8];
    float mx = s;
    #pragma unroll
    for (int o = 1; o < 64; o <<= 1) mx = fmaxf(mx, __shfl_xor(mx, o));
    int wid = l >> 6;
    if ((l & 63) == 0) red[wid] = mx;
    __syncthreads();
    mx = red[0];
    #pragma unroll
    for (int p = 1; p < 8; ++p) mx = fmaxf(mx, red[p]);
    __syncthreads();
    float e = expf(s - mx) * mask[m];
    float sm = e;
    #pragma unroll
    for (int o = 1; o < 64; o <<= 1) sm += __shfl_xor(sm, o);
    if ((l & 63) == 0) red[wid] = sm;
    __syncthreads();
    float tot = 0.f;
    #pragma unroll
    for (int p = 0; p < 8; ++p) tot += red[p];
    float alpha = e / tot;
    out_alpha[m]  = alpha;
    out_newcov[m] = cov[m] + alpha;
}

// -------------------------------------------------------------------------
__global__ __launch_bounds__(256) void cqt_bf_kernel(
    const float* __restrict__ alpha, const ushort* __restrict__ Abf,
    float* __restrict__ out)
{
    int b = blockIdx.y;
    int k = blockIdx.x * 256 + threadIdx.x;
    __shared__ float al[L_];
    al[threadIdx.x]       = alpha[b * L_ + threadIdx.x];
    al[threadIdx.x + 256] = alpha[b * L_ + threadIdx.x + 256];
    __syncthreads();
    float acc = 0.f;
    const ushort* p = &Abf[(size_t)b * L_ * H2_ + k];
    #pragma unroll 8
    for (int l = 0; l < L_; ++l) {
        float v = __uint_as_float((uint)p[(size_t)l * H2_] << 16);
        acc += al[l] * v;
    }
    out[b * H2_ + k] = acc;
}

__global__ __launch_bounds__(256) void cqt_kernel(
    const float* __restrict__ alpha, const float* __restrict__ pai_q,
    float* __restrict__ out)
{
    int b = blockIdx.y;
    int k = blockIdx.x * 256 + threadIdx.x;
    __shared__ float al[L_];
    al[threadIdx.x]       = alpha[b * L_ + threadIdx.x];
    al[threadIdx.x + 256] = alpha[b * L_ + threadIdx.x + 256];
    __syncthreads();
    float acc = 0.f;
    const float* p = &pai_q[(size_t)b * L_ * H2_ + k];
    #pragma unroll 8
    for (int l = 0; l < L_; ++l) acc += al[l] * p[(size_t)l * H2_];
    out[b * H2_ + k] = acc;
}

extern "C" void kernel_launch(void* const* d_in, const int* in_sizes, int n_in,
                              void* d_out, int out_size, void* d_ws, size_t ws_size,
                              hipStream_t stream)
{
    const float* s_t_hat = (const float*)d_in[0];
    const float* pai_q   = (const float*)d_in[1];
    const float* mask    = (const float*)d_in[2];
    const float* cov     = (const float*)d_in[3];
    const float* W_q     = (const float*)d_in[4];
    const float* W_qs_w  = (const float*)d_in[5];
    const float* W_qs_b  = (const float*)d_in[6];
    const float* W_c     = (const float*)d_in[7];
    const float* v_q     = (const float*)d_in[8];

    float* out     = (float*)d_out;
    float* c_q_t   = out;
    float* alpha   = out + B_ * H2_;
    float* newcov  = alpha + B_ * L_;

    // ws: dec 262144 | scores_part 2097152 | Bbf 2097152 | Abf 67108864
    // dec_part (4 MB) time-aliases Abf (used before convertA writes it).
    char* ws = (char*)d_ws;
    float*  dec         = (float*)ws;
    float*  scores_part = (float*)(ws + 262144);
    ushort* Bbf         = (ushort*)(ws + 262144 + 2097152);
    ushort* Abf         = (ushort*)(ws + 262144 + 2097152 + 2097152);
    float*  dec_part    = (float*)Abf;
    const size_t ws_needed = 262144ull + 2097152ull + 2097152ull + 67108864ull;

    if (ws_size >= ws_needed) {
        dec_split_kernel<<<dim3(16, KSPLIT), 256, 0, stream>>>(s_t_hat, W_qs_w, dec_part);
        dec_reduce_kernel<<<dim3(B_ * H2_ / 256), 256, 0, stream>>>(dec_part, W_qs_b, dec);
        convertA_kernel<<<dim3((M_ * H2_) / (256 * 8)), 256, 0, stream>>>(pai_q, Abf);
        convertB_kernel<<<dim3(32, 32), 256, 0, stream>>>(W_q, Bbf);
        score_kernel5<<<dim3((M_ / BM5) * (H2_ / BN5)), 512, 0, stream>>>(
            Abf, Bbf, dec, cov, W_c, v_q, scores_part);
        softmax_kernel<<<dim3(B_), 512, 0, stream>>>(scores_part, mask, cov, alpha, newcov);
        cqt_bf_kernel<<<dim3(4, B_), 256, 0, stream>>>(alpha, Abf, c_q_t);
    } else {
        dec_kernel<<<dim3(4, 16), 256, 0, stream>>>(s_t_hat, W_qs_w, W_qs_b, dec);
        score_kernel_fb<<<dim3(M_ / BM, H2_ / BN), 256, 0, stream>>>(
            pai_q, W_q, dec, cov, W_c, v_q, scores_part);
        softmax_kernel<<<dim3(B_), 512, 0, stream>>>(scores_part, mask, cov, alpha, newcov);
        cqt_kernel<<<dim3(4, B_), 256, 0, stream>>>(alpha, pai_q, c_q_t);
    }
}

// Round 12
// 191.219 us; speedup vs baseline: 1.0479x; 1.0479x over previous
//
#include <hip/hip_runtime.h>
#include <hip/hip_bf16.h>

#define B_   64
#define L_   512
#define H2_  1024
#define M_   (B_ * L_)     // 32768
#define KSPLIT 16
#define KCH  (H2_ / KSPLIT)   // 64

typedef short bf16x8 __attribute__((ext_vector_type(8)));
typedef float f32x4  __attribute__((ext_vector_type(4)));
typedef ushort ushort8_t __attribute__((ext_vector_type(8)));

__device__ __forceinline__ ushort f2bf(float f) {
    uint x = __float_as_uint(f);
    uint r = (x + 0x7FFFu + ((x >> 16) & 1u)) >> 16;
    return (ushort)r;
}

__device__ __forceinline__ float fast_tanh(float x) {
    float ax = fabsf(x);
    float e  = __expf(-2.0f * ax);
    float t  = 1.0f - 2.0f * e / (1.0f + e);
    return copysignf(t, x);
}

__device__ __forceinline__ void gload_lds16(const ushort* g, ushort* l) {
    __builtin_amdgcn_global_load_lds(
        (const __attribute__((address_space(1))) void*)g,
        (__attribute__((address_space(3))) void*)l, 16, 0, 0);
}

// -------------------------------------------------------------------------
// convertB: W_q [k][n] fp32 -> Bbf [n][k] bf16 (transpose via LDS 32x33).
// -------------------------------------------------------------------------
__global__ __launch_bounds__(256) void convertB_kernel(
    const float* __restrict__ W, ushort* __restrict__ out)
{
    __shared__ float t[32][33];
    int tx = threadIdx.x & 31, ty = threadIdx.x >> 5;
    int k0 = blockIdx.x * 32, n0 = blockIdx.y * 32;
    #pragma unroll
    for (int r = 0; r < 4; ++r)
        t[ty + r * 8][tx] = W[(size_t)(k0 + ty + r * 8) * H2_ + n0 + tx];
    __syncthreads();
    #pragma unroll
    for (int r = 0; r < 4; ++r)
        out[(size_t)(n0 + ty + r * 8) * H2_ + k0 + tx] = f2bf(t[tx][ty + r * 8]);
}

// -------------------------------------------------------------------------
// dec split-K
// -------------------------------------------------------------------------
__global__ __launch_bounds__(256) void dec_split_kernel(
    const float* __restrict__ s_t_hat, const float* __restrict__ Wqs,
    float* __restrict__ dec_part)
{
    const int t  = threadIdx.x;
    const int n  = blockIdx.x * 64 + (t & 63);
    const int k0 = blockIdx.y * KCH;
    const int bg = t >> 6;

    float acc[16];
    #pragma unroll
    for (int i = 0; i < 16; ++i) acc[i] = 0.f;

    for (int k8 = 0; k8 < KCH; k8 += 8) {
        float w[8];
        #pragma unroll
        for (int kk = 0; kk < 8; ++kk)
            w[kk] = Wqs[(size_t)(k0 + k8 + kk) * H2_ + n];
        #pragma unroll
        for (int i = 0; i < 16; ++i) {
            const float* srow = &s_t_hat[(bg * 16 + i) * H2_ + k0 + k8];
            #pragma unroll
            for (int kk = 0; kk < 8; ++kk)
                acc[i] += srow[kk] * w[kk];
        }
    }
    #pragma unroll
    for (int i = 0; i < 16; ++i)
        dec_part[(size_t)blockIdx.y * (B_ * H2_) + (bg * 16 + i) * H2_ + n] = acc[i];
}

__global__ __launch_bounds__(256) void dec_reduce_kernel(
    const float* __restrict__ dec_part, const float* __restrict__ bqs,
    float* __restrict__ dec)
{
    int i = blockIdx.x * 256 + threadIdx.x;
    float s = bqs[i & (H2_ - 1)];
    #pragma unroll
    for (int p = 0; p < KSPLIT; ++p) s += dec_part[(size_t)p * (B_ * H2_) + i];
    dec[i] = s;
}

// -------------------------------------------------------------------------
// Fallback dec (monolithic) — only if ws too small.
// -------------------------------------------------------------------------
__global__ __launch_bounds__(256) void dec_kernel(
    const float* __restrict__ s_t_hat, const float* __restrict__ Wqs,
    const float* __restrict__ bqs, float* __restrict__ dec)
{
    int n  = blockIdx.x * 256 + threadIdx.x;
    int b0 = blockIdx.y * 4;
    float a0 = 0.f, a1 = 0.f, a2 = 0.f, a3 = 0.f;
    for (int h = 0; h < H2_; ++h) {
        float w = Wqs[h * H2_ + n];
        a0 += s_t_hat[(b0 + 0) * H2_ + h] * w;
        a1 += s_t_hat[(b0 + 1) * H2_ + h] * w;
        a2 += s_t_hat[(b0 + 2) * H2_ + h] * w;
        a3 += s_t_hat[(b0 + 3) * H2_ + h] * w;
    }
    float bias = bqs[n];
    dec[(b0 + 0) * H2_ + n] = a0 + bias;
    dec[(b0 + 1) * H2_ + n] = a1 + bias;
    dec[(b0 + 2) * H2_ + n] = a2 + bias;
    dec[(b0 + 3) * H2_ + n] = a3 + bias;
}

// -------------------------------------------------------------------------
// score v6: v3 structure (BK=64, single-buffer, 4 waves, XOR-swizzled LDS)
// with A reg-staged DIRECTLY from fp32 pai_q (no convertA pre-pass):
//   global float4 x2 -> cvt bf16 -> swizzled ds_write_b128.
// B stays gload_lds with source-preswizzle (involution identical to v3).
// XCD-chunked n-fastest 1D grid (proven FETCH 148->47 MB in v4).
// -------------------------------------------------------------------------
#define BM6 128
#define BN6 128
#define BK6 64

__global__ __launch_bounds__(256) void score_kernel6(
    const float*  __restrict__ Afp,  // pai_q fp32 (M, 1024)
    const ushort* __restrict__ Bbf,  // (1024 n, 1024 k) bf16
    const float* __restrict__ dec,
    const float* __restrict__ cov,
    const float* __restrict__ Wc,
    const float* __restrict__ vq,
    float* __restrict__ scores_part) // (16, M)
{
    __shared__ ushort As6[BM6 * BK6];
    __shared__ ushort Bs6[BN6 * BK6];

    const int tid  = threadIdx.x;
    const int lane = tid & 63;
    const int wave = tid >> 6;
    const int wm = wave >> 1, wn = wave & 1;

    // XCD-chunked, n-fastest swizzle over 2048 blocks (bijective)
    const int bid  = blockIdx.x;
    const int xcd  = bid & 7;
    const int slot = bid >> 3;           // 0..255
    const int mb   = xcd * 32 + (slot >> 3);   // 0..255
    const int nbk  = slot & 7;                  // 0..7
    const int m0   = mb * BM6;
    const int n0   = nbk * BN6;

    f32x4 acc[4][4] = {};

    // B staging via gload_lds: per wave 32 rows x 128B, source pre-swizzled
    const int srow = lane >> 3;               // 0..7
    const int scol = ((lane & 7) ^ srow) * 8;
    const size_t bbase = (size_t)(n0 + wave * 32 + srow) * H2_ + scol;
    ushort* lB = Bs6 + wave * 32 * BK6;

    // A reg-staging mapping: thread -> (row = ar+p*32, logical chunk alc)
    const int ar  = tid >> 3;                 // 0..31
    const int alc = tid & 7;                  // 0..7

    const int fr = lane & 15;
    const int fg = lane >> 4;
    const int fx = fr & 7;

    for (int kt = 0; kt < H2_; kt += BK6) {
        // B: 4 async gload_lds (issued first, in flight during A staging)
        #pragma unroll
        for (int p = 0; p < 4; ++p)
            gload_lds16(Bbf + bbase + (size_t)p * 8 * H2_ + kt, lB + p * 8 * BK6);

        // A: 4 reg-staged passes (fp32 -> bf16 -> swizzled ds_write_b128)
        #pragma unroll
        for (int p = 0; p < 4; ++p) {
            int row = ar + p * 32;
            const float* gp = &Afp[(size_t)(m0 + row) * H2_ + kt + alc * 8];
            float4 v0 = *(const float4*)gp;
            float4 v1 = *(const float4*)(gp + 4);
            ushort8_t h;
            h[0] = f2bf(v0.x); h[1] = f2bf(v0.y); h[2] = f2bf(v0.z); h[3] = f2bf(v0.w);
            h[4] = f2bf(v1.x); h[5] = f2bf(v1.y); h[6] = f2bf(v1.z); h[7] = f2bf(v1.w);
            *(ushort8_t*)&As6[row * BK6 + ((alc ^ (row & 7)) * 8)] = h;
        }
        __syncthreads();   // drains vmcnt (gload_lds) + lgkm (ds_write)

        bf16x8 af[4][2];
        #pragma unroll
        for (int i = 0; i < 4; ++i)
            #pragma unroll
            for (int ks = 0; ks < 2; ++ks)
                af[i][ks] = *(const bf16x8*)
                    &As6[(wm * 64 + i * 16 + fr) * BK6 + (((fg + ks * 4) ^ fx) * 8)];

        #pragma unroll
        for (int j = 0; j < 4; ++j) {
            bf16x8 b0 = *(const bf16x8*)
                &Bs6[(wn * 64 + j * 16 + fr) * BK6 + ((fg ^ fx) * 8)];
            bf16x8 b1 = *(const bf16x8*)
                &Bs6[(wn * 64 + j * 16 + fr) * BK6 + (((fg + 4) ^ fx) * 8)];
            #pragma unroll
            for (int i = 0; i < 4; ++i) {
                acc[i][j] = __builtin_amdgcn_mfma_f32_16x16x32_bf16(af[i][0], b0, acc[i][j], 0, 0, 0);
                acc[i][j] = __builtin_amdgcn_mfma_f32_16x16x32_bf16(af[i][1], b1, acc[i][j], 0, 0, 0);
            }
        }
        __syncthreads();
    }

    // ---- epilogue: + dec + cov*Wc -> tanh -> * vq -> row-sum -> partial ----
    const int b = m0 >> 9;
    float dec4[4], wc4[4], vq4[4];
    #pragma unroll
    for (int j = 0; j < 4; ++j) {
        int n = n0 + wn * 64 + j * 16 + fr;
        dec4[j] = dec[b * H2_ + n];
        wc4[j]  = Wc[n];
        vq4[j]  = vq[n];
    }
    #pragma unroll
    for (int i = 0; i < 4; ++i) {
        #pragma unroll
        for (int r = 0; r < 4; ++r) {
            int ml = wm * 64 + i * 16 + fg * 4 + r;
            int m  = m0 + ml;
            float cv = cov[b * L_ + (m & (L_ - 1))];
            float s = 0.f;
            #pragma unroll
            for (int j = 0; j < 4; ++j) {
                float att = acc[i][j][r] + dec4[j] + cv * wc4[j];
                s += fast_tanh(att) * vq4[j];
            }
            s += __shfl_xor(s, 1);
            s += __shfl_xor(s, 2);
            s += __shfl_xor(s, 4);
            s += __shfl_xor(s, 8);
            if (fr == 0)
                scores_part[(size_t)(nbk * 2 + wn) * M_ + m] = s;
        }
    }
}

// -------------------------------------------------------------------------
// Fallback score (fp32 inputs, reg-staged both) — only if ws too small.
// -------------------------------------------------------------------------
#define BM 128
#define BN 128
#define LDK 40
__global__ __launch_bounds__(256) void score_kernel_fb(
    const float* __restrict__ A, const float* __restrict__ Bmat,
    const float* __restrict__ dec, const float* __restrict__ cov,
    const float* __restrict__ Wc, const float* __restrict__ vq,
    float* __restrict__ scores_part)
{
    __shared__ ushort As[BM * LDK];
    __shared__ ushort Bs[BN * LDK];
    const int tid  = threadIdx.x;
    const int lane = tid & 63;
    const int wave = tid >> 6;
    const int wm = wave >> 1, wn = wave & 1;
    const int m0 = blockIdx.x * BM;
    const int n0 = blockIdx.y * BN;
    f32x4 acc[4][4] = {};
    const int a_row = tid >> 3;
    const int a_kc  = (tid & 7) * 4;
    const int b_k  = tid >> 5;
    const int b_nc = (tid & 31) * 4;
    const int fr = lane & 15;
    const int fg = lane >> 4;
    for (int kt = 0; kt < H2_; kt += 32) {
        #pragma unroll
        for (int p = 0; p < 4; ++p) {
            int row = a_row + p * 32;
            float4 v = *(const float4*)&A[(size_t)(m0 + row) * H2_ + kt + a_kc];
            ushort4 h;
            h.x = f2bf(v.x); h.y = f2bf(v.y); h.z = f2bf(v.z); h.w = f2bf(v.w);
            *(ushort4*)&As[row * LDK + a_kc] = h;
        }
        #pragma unroll
        for (int p = 0; p < 4; ++p) {
            int k = b_k + p * 8;
            float4 v = *(const float4*)&Bmat[(size_t)(kt + k) * H2_ + n0 + b_nc];
            Bs[(b_nc + 0) * LDK + k] = f2bf(v.x);
            Bs[(b_nc + 1) * LDK + k] = f2bf(v.y);
            Bs[(b_nc + 2) * LDK + k] = f2bf(v.z);
            Bs[(b_nc + 3) * LDK + k] = f2bf(v.w);
        }
        __syncthreads();
        bf16x8 af[4], bfr[4];
        #pragma unroll
        for (int i = 0; i < 4; ++i)
            af[i] = *(const bf16x8*)&As[(wm * 64 + i * 16 + fr) * LDK + fg * 8];
        #pragma unroll
        for (int j = 0; j < 4; ++j)
            bfr[j] = *(const bf16x8*)&Bs[(wn * 64 + j * 16 + fr) * LDK + fg * 8];
        #pragma unroll
        for (int i = 0; i < 4; ++i)
            #pragma unroll
            for (int j = 0; j < 4; ++j)
                acc[i][j] = __builtin_amdgcn_mfma_f32_16x16x32_bf16(af[i], bfr[j], acc[i][j], 0, 0, 0);
        __syncthreads();
    }
    const int b = m0 >> 9;
    float dec4[4], wc4[4], vq4[4];
    #pragma unroll
    for (int j = 0; j < 4; ++j) {
        int n = n0 + wn * 64 + j * 16 + fr;
        dec4[j] = dec[b * H2_ + n];
        wc4[j]  = Wc[n];
        vq4[j]  = vq[n];
    }
    #pragma unroll
    for (int i = 0; i < 4; ++i) {
        #pragma unroll
        for (int r = 0; r < 4; ++r) {
            int ml = wm * 64 + i * 16 + fg * 4 + r;
            int m  = m0 + ml;
            float cv = cov[b * L_ + (m & (L_ - 1))];
            float s = 0.f;
            #pragma unroll
            for (int j = 0; j < 4; ++j) {
                float att = acc[i][j][r] + dec4[j] + cv * wc4[j];
                s += fast_tanh(att) * vq4[j];
            }
            s += __shfl_xor(s, 1);
            s += __shfl_xor(s, 2);
            s += __shfl_xor(s, 4);
            s += __shfl_xor(s, 8);
            if (fr == 0)
                scores_part[(size_t)(blockIdx.y * 2 + wn) * M_ + m] = s;
        }
    }
}

// -------------------------------------------------------------------------
__global__ __launch_bounds__(512) void softmax_kernel(
    const float* __restrict__ scores_part,
    const float* __restrict__ mask,
    const float* __restrict__ cov,
    float* __restrict__ out_alpha,
    float* __restrict__ out_newcov)
{
    int b = blockIdx.x;
    int l = threadIdx.x;
    int m = b * L_ + l;
    float s = 0.f;
    #pragma unroll
    for (int p = 0; p < 16; ++p) s += scores_part[(size_t)p * M_ + m];
    __shared__ float red[8];
    float mx = s;
    #pragma unroll
    for (int o = 1; o < 64; o <<= 1) mx = fmaxf(mx, __shfl_xor(mx, o));
    int wid = l >> 6;
    if ((l & 63) == 0) red[wid] = mx;
    __syncthreads();
    mx = red[0];
    #pragma unroll
    for (int p = 1; p < 8; ++p) mx = fmaxf(mx, red[p]);
    __syncthreads();
    float e = expf(s - mx) * mask[m];
    float sm = e;
    #pragma unroll
    for (int o = 1; o < 64; o <<= 1) sm += __shfl_xor(sm, o);
    if ((l & 63) == 0) red[wid] = sm;
    __syncthreads();
    float tot = 0.f;
    #pragma unroll
    for (int p = 0; p < 8; ++p) tot += red[p];
    float alpha = e / tot;
    out_alpha[m]  = alpha;
    out_newcov[m] = cov[m] + alpha;
}

// -------------------------------------------------------------------------
// cqt from fp32 pai_q (L3-resident after score read it)
// -------------------------------------------------------------------------
__global__ __launch_bounds__(256) void cqt_kernel(
    const float* __restrict__ alpha, const float* __restrict__ pai_q,
    float* __restrict__ out)
{
    int b = blockIdx.y;
    int k = blockIdx.x * 256 + threadIdx.x;
    __shared__ float al[L_];
    al[threadIdx.x]       = alpha[b * L_ + threadIdx.x];
    al[threadIdx.x + 256] = alpha[b * L_ + threadIdx.x + 256];
    __syncthreads();
    float acc = 0.f;
    const float* p = &pai_q[(size_t)b * L_ * H2_ + k];
    #pragma unroll 8
    for (int l = 0; l < L_; ++l) acc += al[l] * p[(size_t)l * H2_];
    out[b * H2_ + k] = acc;
}

extern "C" void kernel_launch(void* const* d_in, const int* in_sizes, int n_in,
                              void* d_out, int out_size, void* d_ws, size_t ws_size,
                              hipStream_t stream)
{
    const float* s_t_hat = (const float*)d_in[0];
    const float* pai_q   = (const float*)d_in[1];
    const float* mask    = (const float*)d_in[2];
    const float* cov     = (const float*)d_in[3];
    const float* W_q     = (const float*)d_in[4];
    const float* W_qs_w  = (const float*)d_in[5];
    const float* W_qs_b  = (const float*)d_in[6];
    const float* W_c     = (const float*)d_in[7];
    const float* v_q     = (const float*)d_in[8];

    float* out     = (float*)d_out;
    float* c_q_t   = out;
    float* alpha   = out + B_ * H2_;
    float* newcov  = alpha + B_ * L_;

    // ws layout: dec 256KB | scores_part 2MB | Bbf 2MB | dec_part 4MB
    char* ws = (char*)d_ws;
    float*  dec         = (float*)ws;
    float*  scores_part = (float*)(ws + 262144);
    ushort* Bbf         = (ushort*)(ws + 262144 + 2097152);
    float*  dec_part    = (float*)(ws + 262144 + 2097152 + 2097152);
    const size_t ws_needed = 262144ull + 2097152ull + 2097152ull + 4194304ull;
    const size_t ws_min_fb = 262144ull + 2097152ull;

    if (ws_size >= ws_needed) {
        dec_split_kernel<<<dim3(16, KSPLIT), 256, 0, stream>>>(s_t_hat, W_qs_w, dec_part);
        dec_reduce_kernel<<<dim3(B_ * H2_ / 256), 256, 0, stream>>>(dec_part, W_qs_b, dec);
        convertB_kernel<<<dim3(32, 32), 256, 0, stream>>>(W_q, Bbf);
        score_kernel6<<<dim3((M_ / BM6) * (H2_ / BN6)), 256, 0, stream>>>(
            pai_q, Bbf, dec, cov, W_c, v_q, scores_part);
        softmax_kernel<<<dim3(B_), 512, 0, stream>>>(scores_part, mask, cov, alpha, newcov);
        cqt_kernel<<<dim3(4, B_), 256, 0, stream>>>(alpha, pai_q, c_q_t);
    } else if (ws_size >= ws_min_fb) {
        dec_kernel<<<dim3(4, 16), 256, 0, stream>>>(s_t_hat, W_qs_w, W_qs_b, dec);
        score_kernel_fb<<<dim3(M_ / BM, H2_ / BN), 256, 0, stream>>>(
            pai_q, W_q, dec, cov, W_c, v_q, scores_part);
        softmax_kernel<<<dim3(B_), 512, 0, stream>>>(scores_part, mask, cov, alpha, newcov);
        cqt_kernel<<<dim3(4, B_), 256, 0, stream>>>(alpha, pai_q, c_q_t);
    }
}

// Round 13
// 185.245 us; speedup vs baseline: 1.0817x; 1.0322x over previous
//
#include <hip/hip_runtime.h>
#include <hip/hip_bf16.h>

#define B_   64
#define L_   512
#define H2_  1024
#define M_   (B_ * L_)     // 32768
#define KSPLIT 16
#define KCH  (H2_ / KSPLIT)   // 64

typedef short bf16x8 __attribute__((ext_vector_type(8)));
typedef float f32x4  __attribute__((ext_vector_type(4)));
typedef ushort ushort8_t __attribute__((ext_vector_type(8)));

__device__ __forceinline__ ushort f2bf(float f) {
    uint x = __float_as_uint(f);
    uint r = (x + 0x7FFFu + ((x >> 16) & 1u)) >> 16;
    return (ushort)r;
}

__device__ __forceinline__ float fast_tanh(float x) {
    float ax = fabsf(x);
    float e  = __expf(-2.0f * ax);
    float t  = 1.0f - 2.0f * e / (1.0f + e);
    return copysignf(t, x);
}

__device__ __forceinline__ void gload_lds16(const ushort* g, ushort* l) {
    __builtin_amdgcn_global_load_lds(
        (const __attribute__((address_space(1))) void*)g,
        (__attribute__((address_space(3))) void*)l, 16, 0, 0);
}

// -------------------------------------------------------------------------
// convertA: pai_q fp32 -> bf16 row-major.
// -------------------------------------------------------------------------
__global__ __launch_bounds__(256) void convertA_kernel(
    const float* __restrict__ in, ushort* __restrict__ out)
{
    size_t i = ((size_t)blockIdx.x * 256 + threadIdx.x) * 8;
    float4 a = *(const float4*)&in[i];
    float4 b = *(const float4*)&in[i + 4];
    ushort8_t h;
    h[0] = f2bf(a.x); h[1] = f2bf(a.y); h[2] = f2bf(a.z); h[3] = f2bf(a.w);
    h[4] = f2bf(b.x); h[5] = f2bf(b.y); h[6] = f2bf(b.z); h[7] = f2bf(b.w);
    *(ushort8_t*)&out[i] = h;
}

// -------------------------------------------------------------------------
// dec split-K
// -------------------------------------------------------------------------
__global__ __launch_bounds__(256) void dec_split_kernel(
    const float* __restrict__ s_t_hat, const float* __restrict__ Wqs,
    float* __restrict__ dec_part)
{
    const int t  = threadIdx.x;
    const int n  = blockIdx.x * 64 + (t & 63);
    const int k0 = blockIdx.y * KCH;
    const int bg = t >> 6;

    float acc[16];
    #pragma unroll
    for (int i = 0; i < 16; ++i) acc[i] = 0.f;

    for (int k8 = 0; k8 < KCH; k8 += 8) {
        float w[8];
        #pragma unroll
        for (int kk = 0; kk < 8; ++kk)
            w[kk] = Wqs[(size_t)(k0 + k8 + kk) * H2_ + n];
        #pragma unroll
        for (int i = 0; i < 16; ++i) {
            const float* srow = &s_t_hat[(bg * 16 + i) * H2_ + k0 + k8];
            #pragma unroll
            for (int kk = 0; kk < 8; ++kk)
                acc[i] += srow[kk] * w[kk];
        }
    }
    #pragma unroll
    for (int i = 0; i < 16; ++i)
        dec_part[(size_t)blockIdx.y * (B_ * H2_) + (bg * 16 + i) * H2_ + n] = acc[i];
}

// -------------------------------------------------------------------------
// fused dec_reduce (blocks 0..255) + convertB transpose (blocks 256..1279)
// Independent data; fusion only trims one launch gap.
// -------------------------------------------------------------------------
__global__ __launch_bounds__(256) void decred_convB_kernel(
    const float* __restrict__ dec_part, const float* __restrict__ bqs,
    float* __restrict__ dec,
    const float* __restrict__ W, ushort* __restrict__ outB)
{
    __shared__ float t[32][33];
    int bid = blockIdx.x;
    if (bid < 256) {
        int i = bid * 256 + threadIdx.x;   // 0..65535
        float s = bqs[i & (H2_ - 1)];
        #pragma unroll
        for (int p = 0; p < KSPLIT; ++p) s += dec_part[(size_t)p * (B_ * H2_) + i];
        dec[i] = s;
    } else {
        int cb = bid - 256;                // 0..1023
        int k0 = (cb & 31) * 32, n0 = (cb >> 5) * 32;
        int tx = threadIdx.x & 31, ty = threadIdx.x >> 5;
        #pragma unroll
        for (int r = 0; r < 4; ++r)
            t[ty + r * 8][tx] = W[(size_t)(k0 + ty + r * 8) * H2_ + n0 + tx];
        __syncthreads();
        #pragma unroll
        for (int r = 0; r < 4; ++r)
            outB[(size_t)(n0 + ty + r * 8) * H2_ + k0 + tx] = f2bf(t[tx][ty + r * 8]);
    }
}

// -------------------------------------------------------------------------
// Fallback dec (monolithic) — only if ws too small.
// -------------------------------------------------------------------------
__global__ __launch_bounds__(256) void dec_kernel(
    const float* __restrict__ s_t_hat, const float* __restrict__ Wqs,
    const float* __restrict__ bqs, float* __restrict__ dec)
{
    int n  = blockIdx.x * 256 + threadIdx.x;
    int b0 = blockIdx.y * 4;
    float a0 = 0.f, a1 = 0.f, a2 = 0.f, a3 = 0.f;
    for (int h = 0; h < H2_; ++h) {
        float w = Wqs[h * H2_ + n];
        a0 += s_t_hat[(b0 + 0) * H2_ + h] * w;
        a1 += s_t_hat[(b0 + 1) * H2_ + h] * w;
        a2 += s_t_hat[(b0 + 2) * H2_ + h] * w;
        a3 += s_t_hat[(b0 + 3) * H2_ + h] * w;
    }
    float bias = bqs[n];
    dec[(b0 + 0) * H2_ + n] = a0 + bias;
    dec[(b0 + 1) * H2_ + n] = a1 + bias;
    dec[(b0 + 2) * H2_ + n] = a2 + bias;
    dec[(b0 + 3) * H2_ + n] = a3 + bias;
}

// -------------------------------------------------------------------------
// score v3 (the measured-best structure): BK=64, XOR-swizzled LDS
// (pre-swizzled gload source + swizzled ds_read), fast tanh epilogue.
// -------------------------------------------------------------------------
#define BM 128
#define BN 128
#define BK 64

__global__ __launch_bounds__(256) void score_kernel3(
    const ushort* __restrict__ Abf,  // (M, 1024) bf16
    const ushort* __restrict__ Bbf,  // (1024 n, 1024 k) bf16
    const float* __restrict__ dec,
    const float* __restrict__ cov,
    const float* __restrict__ Wc,
    const float* __restrict__ vq,
    float* __restrict__ scores_part) // (16, M)
{
    __shared__ ushort As[BM * BK];
    __shared__ ushort Bs[BN * BK];

    const int tid  = threadIdx.x;
    const int lane = tid & 63;
    const int wave = tid >> 6;
    const int wm = wave >> 1, wn = wave & 1;
    const int m0 = blockIdx.x * BM;
    const int n0 = blockIdx.y * BN;

    f32x4 acc[4][4] = {};

    const int srow = lane >> 3;               // 0..7
    const int scol = ((lane & 7) ^ srow) * 8; // swizzled ushort offset
    const size_t abase = (size_t)(m0 + wave * 32 + srow) * H2_ + scol;
    const size_t bbase = (size_t)(n0 + wave * 32 + srow) * H2_ + scol;
    ushort* lA = As + wave * 32 * BK;
    ushort* lB = Bs + wave * 32 * BK;

    const int fr = lane & 15;
    const int fg = lane >> 4;
    const int fx = fr & 7;

    for (int kt = 0; kt < H2_; kt += BK) {
        #pragma unroll
        for (int p = 0; p < 4; ++p) {
            gload_lds16(Abf + abase + p * 8 * H2_ + kt, lA + p * 8 * BK);
            gload_lds16(Bbf + bbase + p * 8 * H2_ + kt, lB + p * 8 * BK);
        }
        __syncthreads();

        bf16x8 af[4][2];
        #pragma unroll
        for (int i = 0; i < 4; ++i)
            #pragma unroll
            for (int ks = 0; ks < 2; ++ks)
                af[i][ks] = *(const bf16x8*)
                    &As[(wm * 64 + i * 16 + fr) * BK + (((fg + ks * 4) ^ fx) * 8)];

        #pragma unroll
        for (int j = 0; j < 4; ++j) {
            bf16x8 b0 = *(const bf16x8*)
                &Bs[(wn * 64 + j * 16 + fr) * BK + ((fg ^ fx) * 8)];
            bf16x8 b1 = *(const bf16x8*)
                &Bs[(wn * 64 + j * 16 + fr) * BK + (((fg + 4) ^ fx) * 8)];
            #pragma unroll
            for (int i = 0; i < 4; ++i) {
                acc[i][j] = __builtin_amdgcn_mfma_f32_16x16x32_bf16(af[i][0], b0, acc[i][j], 0, 0, 0);
                acc[i][j] = __builtin_amdgcn_mfma_f32_16x16x32_bf16(af[i][1], b1, acc[i][j], 0, 0, 0);
            }
        }
        __syncthreads();
    }

    const int b = m0 >> 9;
    float dec4[4], wc4[4], vq4[4];
    #pragma unroll
    for (int j = 0; j < 4; ++j) {
        int n = n0 + wn * 64 + j * 16 + fr;
        dec4[j] = dec[b * H2_ + n];
        wc4[j]  = Wc[n];
        vq4[j]  = vq[n];
    }
    #pragma unroll
    for (int i = 0; i < 4; ++i) {
        #pragma unroll
        for (int r = 0; r < 4; ++r) {
            int ml = wm * 64 + i * 16 + fg * 4 + r;
            int m  = m0 + ml;
            float cv = cov[b * L_ + (m & (L_ - 1))];
            float s = 0.f;
            #pragma unroll
            for (int j = 0; j < 4; ++j) {
                float att = acc[i][j][r] + dec4[j] + cv * wc4[j];
                s += fast_tanh(att) * vq4[j];
            }
            s += __shfl_xor(s, 1);
            s += __shfl_xor(s, 2);
            s += __shfl_xor(s, 4);
            s += __shfl_xor(s, 8);
            if (fr == 0)
                scores_part[(size_t)(blockIdx.y * 2 + wn) * M_ + m] = s;
        }
    }
}

// -------------------------------------------------------------------------
// Fallback score (fp32 inputs, reg-staged) — only if ws too small.
// -------------------------------------------------------------------------
#define LDK 40
__global__ __launch_bounds__(256) void score_kernel_fb(
    const float* __restrict__ A, const float* __restrict__ Bmat,
    const float* __restrict__ dec, const float* __restrict__ cov,
    const float* __restrict__ Wc, const float* __restrict__ vq,
    float* __restrict__ scores_part)
{
    __shared__ ushort As[BM * LDK];
    __shared__ ushort Bs[BN * LDK];
    const int tid  = threadIdx.x;
    const int lane = tid & 63;
    const int wave = tid >> 6;
    const int wm = wave >> 1, wn = wave & 1;
    const int m0 = blockIdx.x * BM;
    const int n0 = blockIdx.y * BN;
    f32x4 acc[4][4] = {};
    const int a_row = tid >> 3;
    const int a_kc  = (tid & 7) * 4;
    const int b_k  = tid >> 5;
    const int b_nc = (tid & 31) * 4;
    const int fr = lane & 15;
    const int fg = lane >> 4;
    for (int kt = 0; kt < H2_; kt += 32) {
        #pragma unroll
        for (int p = 0; p < 4; ++p) {
            int row = a_row + p * 32;
            float4 v = *(const float4*)&A[(size_t)(m0 + row) * H2_ + kt + a_kc];
            ushort4 h;
            h.x = f2bf(v.x); h.y = f2bf(v.y); h.z = f2bf(v.z); h.w = f2bf(v.w);
            *(ushort4*)&As[row * LDK + a_kc] = h;
        }
        #pragma unroll
        for (int p = 0; p < 4; ++p) {
            int k = b_k + p * 8;
            float4 v = *(const float4*)&Bmat[(size_t)(kt + k) * H2_ + n0 + b_nc];
            Bs[(b_nc + 0) * LDK + k] = f2bf(v.x);
            Bs[(b_nc + 1) * LDK + k] = f2bf(v.y);
            Bs[(b_nc + 2) * LDK + k] = f2bf(v.z);
            Bs[(b_nc + 3) * LDK + k] = f2bf(v.w);
        }
        __syncthreads();
        bf16x8 af[4], bfr[4];
        #pragma unroll
        for (int i = 0; i < 4; ++i)
            af[i] = *(const bf16x8*)&As[(wm * 64 + i * 16 + fr) * LDK + fg * 8];
        #pragma unroll
        for (int j = 0; j < 4; ++j)
            bfr[j] = *(const bf16x8*)&Bs[(wn * 64 + j * 16 + fr) * LDK + fg * 8];
        #pragma unroll
        for (int i = 0; i < 4; ++i)
            #pragma unroll
            for (int j = 0; j < 4; ++j)
                acc[i][j] = __builtin_amdgcn_mfma_f32_16x16x32_bf16(af[i], bfr[j], acc[i][j], 0, 0, 0);
        __syncthreads();
    }
    const int b = m0 >> 9;
    float dec4[4], wc4[4], vq4[4];
    #pragma unroll
    for (int j = 0; j < 4; ++j) {
        int n = n0 + wn * 64 + j * 16 + fr;
        dec4[j] = dec[b * H2_ + n];
        wc4[j]  = Wc[n];
        vq4[j]  = vq[n];
    }
    #pragma unroll
    for (int i = 0; i < 4; ++i) {
        #pragma unroll
        for (int r = 0; r < 4; ++r) {
            int ml = wm * 64 + i * 16 + fg * 4 + r;
            int m  = m0 + ml;
            float cv = cov[b * L_ + (m & (L_ - 1))];
            float s = 0.f;
            #pragma unroll
            for (int j = 0; j < 4; ++j) {
                float att = acc[i][j][r] + dec4[j] + cv * wc4[j];
                s += fast_tanh(att) * vq4[j];
            }
            s += __shfl_xor(s, 1);
            s += __shfl_xor(s, 2);
            s += __shfl_xor(s, 4);
            s += __shfl_xor(s, 8);
            if (fr == 0)
                scores_part[(size_t)(blockIdx.y * 2 + wn) * M_ + m] = s;
        }
    }
}

// -------------------------------------------------------------------------
__global__ __launch_bounds__(512) void softmax_kernel(
    const float* __restrict__ scores_part,
    const float* __restrict__ mask,
    const float* __restrict__ cov,
    float* __restrict__ out_alpha,
    float* __restrict__ out_newcov)
{
    int b = blockIdx.x;
    int l = threadIdx.x;
    int m = b * L_ + l;
    float s = 0.f;
    #pragma unroll
    for (int p = 0; p < 16; ++p) s += scores_part[(size_t)p * M_ + m];
    __shared__ float red[8];
    float mx = s;
    #pragma unroll
    for (int o = 1; o < 64; o <<= 1) mx = fmaxf(mx, __shfl_xor(mx, o));
    int wid = l >> 6;
    if ((l & 63) == 0) red[wid] = mx;
    __syncthreads();
    mx = red[0];
    #pragma unroll
    for (int p = 1; p < 8; ++p) mx = fmaxf(mx, red[p]);
    __syncthreads();
    float e = expf(s - mx) * mask[m];
    float sm = e;
    #pragma unroll
    for (int o = 1; o < 64; o <<= 1) sm += __shfl_xor(sm, o);
    if ((l & 63) == 0) red[wid] = sm;
    __syncthreads();
    float tot = 0.f;
    #pragma unroll
    for (int p = 0; p < 8; ++p) tot += red[p];
    float alpha = e / tot;
    out_alpha[m]  = alpha;
    out_newcov[m] = cov[m] + alpha;
}

// -------------------------------------------------------------------------
__global__ __launch_bounds__(256) void cqt_bf_kernel(
    const float* __restrict__ alpha, const ushort* __restrict__ Abf,
    float* __restrict__ out)
{
    int b = blockIdx.y;
    int k = blockIdx.x * 256 + threadIdx.x;
    __shared__ float al[L_];
    al[threadIdx.x]       = alpha[b * L_ + threadIdx.x];
    al[threadIdx.x + 256] = alpha[b * L_ + threadIdx.x + 256];
    __syncthreads();
    float acc = 0.f;
    const ushort* p = &Abf[(size_t)b * L_ * H2_ + k];
    #pragma unroll 8
    for (int l = 0; l < L_; ++l) {
        float v = __uint_as_float((uint)p[(size_t)l * H2_] << 16);
        acc += al[l] * v;
    }
    out[b * H2_ + k] = acc;
}

__global__ __launch_bounds__(256) void cqt_kernel(
    const float* __restrict__ alpha, const float* __restrict__ pai_q,
    float* __restrict__ out)
{
    int b = blockIdx.y;
    int k = blockIdx.x * 256 + threadIdx.x;
    __shared__ float al[L_];
    al[threadIdx.x]       = alpha[b * L_ + threadIdx.x];
    al[threadIdx.x + 256] = alpha[b * L_ + threadIdx.x + 256];
    __syncthreads();
    float acc = 0.f;
    const float* p = &pai_q[(size_t)b * L_ * H2_ + k];
    #pragma unroll 8
    for (int l = 0; l < L_; ++l) acc += al[l] * p[(size_t)l * H2_];
    out[b * H2_ + k] = acc;
}

extern "C" void kernel_launch(void* const* d_in, const int* in_sizes, int n_in,
                              void* d_out, int out_size, void* d_ws, size_t ws_size,
                              hipStream_t stream)
{
    const float* s_t_hat = (const float*)d_in[0];
    const float* pai_q   = (const float*)d_in[1];
    const float* mask    = (const float*)d_in[2];
    const float* cov     = (const float*)d_in[3];
    const float* W_q     = (const float*)d_in[4];
    const float* W_qs_w  = (const float*)d_in[5];
    const float* W_qs_b  = (const float*)d_in[6];
    const float* W_c     = (const float*)d_in[7];
    const float* v_q     = (const float*)d_in[8];

    float* out     = (float*)d_out;
    float* c_q_t   = out;
    float* alpha   = out + B_ * H2_;
    float* newcov  = alpha + B_ * L_;

    // ws: dec 262144 | scores_part 2097152 | Bbf 2097152 | Abf 67108864
    // dec_part (4 MB) time-aliases Abf (used before convertA writes it).
    char* ws = (char*)d_ws;
    float*  dec         = (float*)ws;
    float*  scores_part = (float*)(ws + 262144);
    ushort* Bbf         = (ushort*)(ws + 262144 + 2097152);
    ushort* Abf         = (ushort*)(ws + 262144 + 2097152 + 2097152);
    float*  dec_part    = (float*)Abf;
    const size_t ws_needed = 262144ull + 2097152ull + 2097152ull + 67108864ull;
    const size_t ws_min_fb = 262144ull + 2097152ull;

    if (ws_size >= ws_needed) {
        dec_split_kernel<<<dim3(16, KSPLIT), 256, 0, stream>>>(s_t_hat, W_qs_w, dec_part);
        decred_convB_kernel<<<dim3(1280), 256, 0, stream>>>(
            dec_part, W_qs_b, dec, W_q, Bbf);
        convertA_kernel<<<dim3((M_ * H2_) / (256 * 8)), 256, 0, stream>>>(pai_q, Abf);
        score_kernel3<<<dim3(M_ / BM, H2_ / BN), 256, 0, stream>>>(
            Abf, Bbf, dec, cov, W_c, v_q, scores_part);
        softmax_kernel<<<dim3(B_), 512, 0, stream>>>(scores_part, mask, cov, alpha, newcov);
        cqt_bf_kernel<<<dim3(4, B_), 256, 0, stream>>>(alpha, Abf, c_q_t);
    } else if (ws_size >= ws_min_fb) {
        dec_kernel<<<dim3(4, 16), 256, 0, stream>>>(s_t_hat, W_qs_w, W_qs_b, dec);
        score_kernel_fb<<<dim3(M_ / BM, H2_ / BN), 256, 0, stream>>>(
            pai_q, W_q, dec, cov, W_c, v_q, scores_part);
        softmax_kernel<<<dim3(B_), 512, 0, stream>>>(scores_part, mask, cov, alpha, newcov);
        cqt_kernel<<<dim3(4, B_), 256, 0, stream>>>(alpha, pai_q, c_q_t);
    }
}